// Round 15
// baseline (176.028 us; speedup 1.0000x reference)
//
#include <hip/hip_runtime.h>
#include <stdint.h>

#define BB    2048
#define DIN   4096
#define DOUT  4096

// ---------------------------------------------------------------------------
// i8 MFMA bit-GEMM. x,m -> ±1 int8; dot± = 2*sums - 4096;
// out = sums > thr  <=>  dot± > 2*thr - 4096. Exact in i32.
//
// R22 post-mortem: best total 169.0; pack below top-5 cut (~40), bgemm
// 43.5-44 (frozen: 14 rounds show its band invariant to schedule/conflicts/
// traffic). Remaining modeled gap: pack ~40 vs ~12us traffic floor. Last
// unexploited mechanism: pack_m's 64-wide tiles read 64B runs per mask row
// = HALF an L2 line; each 128B line fetched twice, half-consumed. R23:
// 128(n) x 128(k) tiles -> 8 lanes x 16B = full 128B line per row. Same
// v_perm micro-transpose, same 17408B/tile LDS ([128][34] u32), same
// frag-major 1KB chunk stores, same tile count (2/block, 512 blocks).
// pack_x + bgemm byte-verbatim R22.
// Predict: pack -> 33-37, total -> 163-166. Falsifier: total >= 168 ->
// pack pinned by unmodeled floor -> declare practical ceiling next round.
// ws: x8f frag-major [rb 64][kp 128][1024B] @0 (8 MB);
//     m8Tf frag-major [nb 128][kp 128][1024B] @8MB (16 MB).
// chunk(rb,kp): rows rb*32..+31, k bytes [kp*32,+32); lane l = row l&31,
// k-half l>>5, 16B -- the R7-verified mfma_i32_32x32x32_i8 operand map.
// ---------------------------------------------------------------------------

using v4i  = __attribute__((ext_vector_type(4)))  int;
using v16i = __attribute__((ext_vector_type(16))) int;

__device__ __forceinline__ void async_load16(const void* g, void* l) {
    __builtin_amdgcn_global_load_lds(
        (const __attribute__((address_space(1))) unsigned int*)g,
        (__attribute__((address_space(3))) unsigned int*)l,
        16, 0, 0);
}

// bytes {0,1} -> {+1, -1(0xFF)}; no cross-byte carries.
__device__ __forceinline__ unsigned int to_pm1(unsigned int c) {
    return c + ((c ^ 0x01010101u) * 255u);
}

// Fused packing, 768 blocks x 512 threads.
// blocks [0,256): x -> x8f, LDS-staged (R22 verbatim).
// blocks [256,768): masks -> m8Tf, TWO 128(n) x 128(k) tiles per block.
__global__ __launch_bounds__(512)
void pack_all(const int* __restrict__ x,
              const void* __restrict__ mraw,
              char* __restrict__ x8f,
              char* __restrict__ m8Tf) {
    __shared__ __align__(16) char buf[34816];
    const int tid = threadIdx.x;
    if (blockIdx.x < 256) {
        const int rb = blockIdx.x >> 2;            // 0..63
        const int kq = blockIdx.x & 3;             // k quarter
        unsigned int (*tlx)[260] = (unsigned int (*)[260])buf;
        const int sub = tid >> 8;                  // 0/1
        const int t2  = tid & 255;                 // int4 index in fragment

        // stage 1: 16 iters x 2 rows; per instr each wave reads 64
        // consecutive int4 = 1KB contiguous of one row fragment.
        const int4* src4 = (const int4*)x;
        #pragma unroll
        for (int i = 0; i < 16; ++i) {
            const int rl  = i * 2 + sub;           // row local 0..31
            const int row = rb * 32 + rl;
            int4 v = src4[(size_t)row * 1024 + kq * 256 + t2];
            unsigned int t = (unsigned int)(v.x & 1) |
                             ((unsigned int)(v.y & 1) << 8) |
                             ((unsigned int)(v.z & 1) << 16) |
                             ((unsigned int)(v.w & 1) << 24);
            tlx[rl][t2] = to_pm1(t);               // u32 = packed bytes 4*t2..+3
        }
        __syncthreads();

        // stage 2: 8 waves x 4 kps; lane l = chunk slot (row l&31, half l>>5);
        // wave store = one contiguous 1KB frag chunk.
        const int l = tid & 63;
        const int w = tid >> 6;                    // 0..7
        #pragma unroll
        for (int j = 0; j < 4; ++j) {
            const int kpl = w * 4 + j;             // 0..31
            uint4 v = *(const uint4*)&tlx[l & 31][kpl * 8 + (l >> 5) * 4];
            *(uint4*)(x8f + (size_t)rb * 131072 +
                      (size_t)(kq * 32 + kpl) * 1024 + l * 16) = v;
        }
    } else {
        // two 128(n) x 128(k) tiles in parallel: sub-block 0/1.
        const int sub = tid >> 8;                  // 0/1
        const int t2  = tid & 255;
        const int tile = (blockIdx.x - 256) * 2 + sub;  // 0..1023
        const int n0 = (tile >> 5) * 128;          // 32 n-tiles
        const int k0 = (tile & 31) * 128;          // 32 k-strips
        unsigned int (*tl)[34] = (unsigned int (*)[34])(buf + sub * 17408);

        // dtype detect (u8-bool vs int32), exact: int32 words are {0,1};
        // u8-bool words exceed 1 unless bytes 1-3 all zero (P ~ 8^-64/wave).
        const unsigned char* mb = (const unsigned char*)mraw;
        const unsigned int pv = *(const unsigned int*)(mb + (t2 & 63) * 4);
        const bool isU8 = __any(pv > 1u);

        // stage 1: thread reads 4 k-rows x 16 n-cols. 8 lanes/row x 16B =
        // one full 128B line per row (u8 path).
        const int kq4  = t2 >> 3;                  // 0..31: k-quad index
        const int nq16 = (t2 & 7) * 16;            // n-group base 0..112
        unsigned int b[4][4];                      // [k-row r][n-word w]
        if (isU8) {
            #pragma unroll
            for (int r = 0; r < 4; ++r) {
                uint4 v = *(const uint4*)(mb + (size_t)(k0 + kq4 * 4 + r) * DOUT
                                          + n0 + nq16);
                b[r][0] = v.x; b[r][1] = v.y; b[r][2] = v.z; b[r][3] = v.w;
            }
        } else {
            const int4* m32 = (const int4*)mraw;
            #pragma unroll
            for (int r = 0; r < 4; ++r)
                #pragma unroll
                for (int q = 0; q < 4; ++q) {
                    int4 v = m32[((size_t)(k0 + kq4 * 4 + r) * DOUT
                                  + n0 + nq16 + q * 4) >> 2];
                    b[r][q] = (unsigned int)(v.x & 1) |
                              ((unsigned int)(v.y & 1) << 8) |
                              ((unsigned int)(v.z & 1) << 16) |
                              ((unsigned int)(v.w & 1) << 24);
                }
        }
        // transpose each 4x4 byte block via v_perm (verified recipe), ±1,
        // write n-major into LDS: word [n][kq4] = bytes k=k0+kq4*4..+3.
        #pragma unroll
        for (int w = 0; w < 4; ++w) {
            unsigned int a0 = b[0][w], a1 = b[1][w], a2 = b[2][w], a3 = b[3][w];
            unsigned int x0 = __builtin_amdgcn_perm(a1, a0, 0x05010400u);
            unsigned int x1 = __builtin_amdgcn_perm(a3, a2, 0x05010400u);
            unsigned int x2 = __builtin_amdgcn_perm(a1, a0, 0x07030602u);
            unsigned int x3 = __builtin_amdgcn_perm(a3, a2, 0x07030602u);
            unsigned int c0 = __builtin_amdgcn_perm(x1, x0, 0x05040100u);
            unsigned int c1 = __builtin_amdgcn_perm(x1, x0, 0x07060302u);
            unsigned int c2 = __builtin_amdgcn_perm(x3, x2, 0x05040100u);
            unsigned int c3 = __builtin_amdgcn_perm(x3, x2, 0x07060302u);
            tl[nq16 + w * 4 + 0][kq4] = to_pm1(c0);
            tl[nq16 + w * 4 + 1][kq4] = to_pm1(c1);
            tl[nq16 + w * 4 + 2][kq4] = to_pm1(c2);
            tl[nq16 + w * 4 + 3][kq4] = to_pm1(c3);
        }
        __syncthreads();

        // stage 2: frag-major out. 16 chunks (nb 4 x kp 4); wave wvp writes
        // idxc = wvp*4+j: nbl = idxc>>2, kpl = idxc&3. Lane l holds
        // (n = nbl*32 + (l&31), k-half l>>5) -> 16B; 1KB coalesced per chunk.
        const int l   = t2 & 63;
        const int wvp = t2 >> 6;
        #pragma unroll
        for (int j = 0; j < 4; ++j) {
            const int idxc = wvp * 4 + j;          // 0..15
            const int nbl  = idxc >> 2;            // 0..3
            const int kpl  = idxc & 3;             // 0..3
            uint4 v = *(const uint4*)&tl[nbl * 32 + (l & 31)]
                                       [kpl * 8 + (l >> 5) * 4];
            const size_t off = (size_t)((n0 >> 5) + nbl) * 131072 +
                               (size_t)((k0 >> 5) + kpl) * 1024 + l * 16;
            *(uint4*)(m8Tf + off) = v;
        }
    }
}

// i8 MFMA GEMM (R21/R22 verbatim): 256(m)x128(n) block tile, 8 waves =
// 2m x 2n x 2k(split-K), wave tile 128x64 (acc[4][2]). BK=128 chunks (32),
// triple-buffer LDS (144 KB), depth-2 prefetch, one raw s_barrier per chunk
// with counted vmcnt(6). Split-K combine via LDS pool. bm = flat&7 = XCD.
__global__ __launch_bounds__(512)
void bgemm(const char* __restrict__ x8f,
           const char* __restrict__ m8Tf,
           const int* __restrict__ thr,
           int* __restrict__ out) {
    const int flat = blockIdx.x;                   // 0..255
    const int bm   = flat & 7;                     // XCD id = A panel
    const int bn   = flat >> 3;                    // 0..31
    const int b0   = bm * 256;                     // m
    const int o0   = bn * 128;                     // n

    const int tid  = threadIdx.x;
    const int lane = tid & 63;
    const int wv   = tid >> 6;           // 0..7
    const int im   = wv & 1;
    const int in_  = (wv >> 1) & 1;
    const int kh   = wv >> 2;            // split-K half
    const int wm   = im * 128;           // wave tile m origin
    const int wn   = in_ * 64;           // wave tile n origin
    const int l31  = lane & 31;
    const int lh   = lane >> 5;

    // 3 buffers x (A 32KB + B 16KB) = 144 KB; pool reused for split-K combine.
    __shared__ __align__(16) char lds[3 * 49152];

    // stage chunk-step c -> buf: 48 x 1KB frag chunks, all linear.
    // 6 global_load_lds per thread (A:4, B:2).
    auto stage = [&](int c, int buf) {
        char* bufA = lds + buf * 49152;
        char* bufB = bufA + 32768;
        const int kp0 = c * 4;
        #pragma unroll
        for (int j = 0; j < 4; ++j) {              // A: 4 chunks/wave
            const int ci = wv * 4 + j;             // 0..31
            const int rb = ci >> 2, kp = ci & 3;
            async_load16(x8f + (size_t)(bm * 8 + rb) * 131072 +
                               (size_t)(kp0 + kp) * 1024 + lane * 16,
                         bufA + ci * 1024 + lane * 16);
        }
        #pragma unroll
        for (int j = 0; j < 2; ++j) {              // B: 2 chunks/wave
            const int ci = wv * 2 + j;             // 0..15
            const int nb = ci >> 2, kp = ci & 3;
            async_load16(m8Tf + (size_t)(bn * 4 + nb) * 131072 +
                                (size_t)(kp0 + kp) * 1024 + lane * 16,
                         bufB + ci * 1024 + lane * 16);
        }
    };

    v16i acc[4][2];
    #pragma unroll
    for (int t = 0; t < 4; ++t)
        #pragma unroll
        for (int u = 0; u < 2; ++u)
            acc[t][u] = (v16i)(0);

    // prologue: depth-2 prefetch (12 loads/thread in flight).
    stage(0, 0);
    stage(1, 1);

    for (int c = 0; c < 32; ++c) {
        // drain exactly stage(c): leave stage(c+1) (6 loads) in flight.
        if (c < 31) asm volatile("s_waitcnt vmcnt(6)" ::: "memory");
        else        asm volatile("s_waitcnt vmcnt(0)" ::: "memory");
        __builtin_amdgcn_s_barrier();  // stage(c) visible everywhere; all
                                       // waves done computing c-1 -> buf free
        if (c < 30) stage(c + 2, (c + 2) % 3);

        const char* bufA = lds + (c % 3) * 49152;
        const char* bufB = bufA + 32768;
        #pragma unroll
        for (int ks = 0; ks < 2; ++ks) {
            const int kp = kh * 2 + ks;            // this wave's kp chunk
            v4i aF[4], bF[2];
            #pragma unroll
            for (int t = 0; t < 4; ++t)
                aF[t] = *(const v4i*)&bufA[((im * 4 + t) * 4 + kp) * 1024
                                           + lane * 16];
            #pragma unroll
            for (int u = 0; u < 2; ++u)
                bF[u] = *(const v4i*)&bufB[((in_ * 2 + u) * 4 + kp) * 1024
                                           + lane * 16];
            #pragma unroll
            for (int t = 0; t < 4; ++t)
                #pragma unroll
                for (int u = 0; u < 2; ++u)
                    acc[t][u] = __builtin_amdgcn_mfma_i32_32x32x32_i8(
                        aF[t], bF[u], acc[t][u], 0, 0, 0);
        }
    }
    __syncthreads();   // all compute done; lds pool free for combine

    // ---- split-K combine. Pair p = (im,in_): waves (p, kh=0) and (p, kh=1)
    // computed the same 128x64 tile over disjoint K halves. Each wave gives
    // one 64-row half via LDS and keeps the other: h=0 keeps t0,1 gives t2,3;
    // h=1 keeps t2,3 gives t0,1. Pool: per pair 8192 i32 (2 halves x 4096).
    int* pool = (int*)lds;                         // 128 KB used
    const int p = wv & 3;
    {
        const int give0 = kh ? 0 : 2;              // first given t
        const int bw_ = p * 8192 + (kh ? 0 : 1) * 4096;
        #pragma unroll
        for (int tt = 0; tt < 2; ++tt) {
            const int t = give0 + tt;
            #pragma unroll
            for (int u = 0; u < 2; ++u)
                #pragma unroll
                for (int r = 0; r < 16; ++r) {
                    const int rowl = (r & 3) + 8 * (r >> 2) + 4 * lh;
                    pool[bw_ + (tt * 32 + rowl) * 64 + u * 32 + l31] = acc[t][u][r];
                }
        }
    }
    __syncthreads();
    const int keep0 = kh ? 2 : 0;
    const int br_ = p * 8192 + kh * 4096;          // partner's gift = my kept rows
    #pragma unroll
    for (int tt = 0; tt < 2; ++tt) {
        const int t = keep0 + tt;
        #pragma unroll
        for (int u = 0; u < 2; ++u)
            #pragma unroll
            for (int r = 0; r < 16; ++r) {
                const int rowl = (r & 3) + 8 * (r >> 2) + 4 * lh;
                acc[t][u][r] += pool[br_ + (tt * 32 + rowl) * 64 + u * 32 + l31];
            }
    }

    // epilogue: out = (dot± > 2*thr - 4096).
    // C/D layout (verified R7): col = lane&31; row = (reg&3)+8*(reg>>2)+4*(lane>>5).
    #pragma unroll
    for (int u = 0; u < 2; ++u) {
        const int o   = o0 + wn + u * 32 + l31;
        const int lim = 2 * thr[o] - DIN;
        #pragma unroll
        for (int tt = 0; tt < 2; ++tt) {
            const int t = keep0 + tt;
            #pragma unroll
            for (int r = 0; r < 16; ++r) {
                const int rowl = (r & 3) + 8 * (r >> 2) + 4 * lh;
                const int b    = b0 + wm + kh * 64 + tt * 32 + rowl;
                out[(size_t)b * DOUT + o] = (acc[t][u][r] > lim) ? 1 : 0;
            }
        }
    }
}

extern "C" void kernel_launch(void* const* d_in, const int* in_sizes, int n_in,
                              void* d_out, int out_size, void* d_ws, size_t ws_size,
                              hipStream_t stream) {
    const int* x          = (const int*)d_in[0];
    const void* masks     = d_in[1];           // bool: u8 or int32 (detected inline)
    const int* thresholds = (const int*)d_in[2];
    int* out              = (int*)d_out;

    char* x8f  = (char*)d_ws;                         // 8 MB frag-major
    char* m8Tf = (char*)d_ws + ((size_t)8 << 20);     // 16 MB frag-major

    pack_all<<<768, 512, 0, stream>>>(x, masks, x8f, m8Tf);
    bgemm<<<256, 512, 0, stream>>>(x8f, m8Tf, thresholds, out);
}

// Round 16
// 169.424 us; speedup vs baseline: 1.0390x; 1.0390x over previous
//
#include <hip/hip_runtime.h>
#include <stdint.h>

#define BB    2048
#define DIN   4096
#define DOUT  4096

// ---------------------------------------------------------------------------
// i8 MFMA bit-GEMM. x,m -> ±1 int8; dot± = 2*sums - 4096;
// out = sums > thr  <=>  dot± > 2*thr - 4096. Exact in i32.
//
// R23 post-mortem: 128-wide pack_m tile REGRESSED (pack 43-50, LDS
// conflicts 393K->917K; [128][34] layout collides banks, 2-line stride
// broke L1 streaming). Falsifier fired (total 176 >= 168) -> per
// pre-commitment, R24 reverts to the best measured kernel (R22, 169.0us)
// and records the practical ceiling:
//   bgemm ~44us = 2.8x the 15.6us i8-MFMA floor; gap = LDS||MFMA
//   serialization + per-chunk rendezvous. Bracketed by 14 variants:
//   phase-splits 54-58, fat-tile 66, 2blk/CU 79, conflicts 3.15M->0 (no
//   change), traffic 33<->70MB (no change). Next lever would be AITER-
//   style inline-asm interleaved K-loop (beyond HIP source; T3/T4/T5
//   ports all regressed on this op).
//   pack ~40us = 3.3x its 12us traffic floor; store-width/scatter/grid/
//   granule all probed; residual = dependent-chain latency at VALU ~5%.
//   Single-dispatch fusion blocked: cooperative launch poisons graph
//   capture (R19 hard-fail).
// ws: x8f frag-major [rb 64][kp 128][1024B] @0 (8 MB);
//     m8Tf frag-major [nb 128][kp 128][1024B] @8MB (16 MB).
// chunk(rb,kp): rows rb*32..+31, k bytes [kp*32,+32); lane l = row l&31,
// k-half l>>5, 16B -- the R7-verified mfma_i32_32x32x32_i8 operand map.
// ---------------------------------------------------------------------------

using v4i  = __attribute__((ext_vector_type(4)))  int;
using v16i = __attribute__((ext_vector_type(16))) int;

__device__ __forceinline__ void async_load16(const void* g, void* l) {
    __builtin_amdgcn_global_load_lds(
        (const __attribute__((address_space(1))) unsigned int*)g,
        (__attribute__((address_space(3))) unsigned int*)l,
        16, 0, 0);
}

// bytes {0,1} -> {+1, -1(0xFF)}; no cross-byte carries.
__device__ __forceinline__ unsigned int to_pm1(unsigned int c) {
    return c + ((c ^ 0x01010101u) * 255u);
}

// Fused packing, 768 blocks x 512 threads (R22 verbatim).
// blocks [0,256): x -> x8f, LDS-staged.
// blocks [256,768): masks -> m8Tf, 2 tiles per block (64n x 256k each).
__global__ __launch_bounds__(512)
void pack_all(const int* __restrict__ x,
              const void* __restrict__ mraw,
              char* __restrict__ x8f,
              char* __restrict__ m8Tf) {
    __shared__ __align__(16) char buf[34816];
    const int tid = threadIdx.x;
    if (blockIdx.x < 256) {
        const int rb = blockIdx.x >> 2;            // 0..63
        const int kq = blockIdx.x & 3;             // k quarter
        unsigned int (*tlx)[260] = (unsigned int (*)[260])buf;
        const int sub = tid >> 8;                  // 0/1
        const int t2  = tid & 255;                 // int4 index in fragment

        // stage 1: 16 iters x 2 rows; per instr each wave reads 64
        // consecutive int4 = 1KB contiguous of one row fragment.
        const int4* src4 = (const int4*)x;
        #pragma unroll
        for (int i = 0; i < 16; ++i) {
            const int rl  = i * 2 + sub;           // row local 0..31
            const int row = rb * 32 + rl;
            int4 v = src4[(size_t)row * 1024 + kq * 256 + t2];
            unsigned int t = (unsigned int)(v.x & 1) |
                             ((unsigned int)(v.y & 1) << 8) |
                             ((unsigned int)(v.z & 1) << 16) |
                             ((unsigned int)(v.w & 1) << 24);
            tlx[rl][t2] = to_pm1(t);               // u32 = packed bytes 4*t2..+3
        }
        __syncthreads();

        // stage 2: 8 waves x 4 kps; lane l = chunk slot (row l&31, half l>>5);
        // wave store = one contiguous 1KB frag chunk.
        const int l = tid & 63;
        const int w = tid >> 6;                    // 0..7
        #pragma unroll
        for (int j = 0; j < 4; ++j) {
            const int kpl = w * 4 + j;             // 0..31
            uint4 v = *(const uint4*)&tlx[l & 31][kpl * 8 + (l >> 5) * 4];
            *(uint4*)(x8f + (size_t)rb * 131072 +
                      (size_t)(kq * 32 + kpl) * 1024 + l * 16) = v;
        }
    } else {
        // two 64(n) x 256(k) tiles in parallel: sub-block 0/1.
        const int sub = tid >> 8;                  // 0/1
        const int t2  = tid & 255;
        const int tile = (blockIdx.x - 256) * 2 + sub;  // 0..1023
        const int n0 = (tile >> 4) * 64;
        const int k0 = (tile & 15) * 256;
        unsigned int (*tl)[68] = (unsigned int (*)[68])(buf + sub * 17408);

        // dtype detect (u8-bool vs int32), exact: int32 words are {0,1};
        // u8-bool words exceed 1 unless bytes 1-3 all zero (P ~ 8^-64/wave).
        const unsigned char* mb = (const unsigned char*)mraw;
        const unsigned int pv = *(const unsigned int*)(mb + (t2 & 63) * 4);
        const bool isU8 = __any(pv > 1u);

        // stage 1: thread reads 4 k-rows x 16 n-cols (16B/lane coalesced).
        const int kq4  = t2 >> 2;                  // 0..63: k-quad index
        const int nq16 = (t2 & 3) * 16;            // n-group base
        unsigned int b[4][4];                      // [k-row r][n-word w]
        if (isU8) {
            #pragma unroll
            for (int r = 0; r < 4; ++r) {
                uint4 v = *(const uint4*)(mb + (size_t)(k0 + kq4 * 4 + r) * DOUT
                                          + n0 + nq16);
                b[r][0] = v.x; b[r][1] = v.y; b[r][2] = v.z; b[r][3] = v.w;
            }
        } else {
            const int4* m32 = (const int4*)mraw;
            #pragma unroll
            for (int r = 0; r < 4; ++r)
                #pragma unroll
                for (int q = 0; q < 4; ++q) {
                    int4 v = m32[((size_t)(k0 + kq4 * 4 + r) * DOUT
                                  + n0 + nq16 + q * 4) >> 2];
                    b[r][q] = (unsigned int)(v.x & 1) |
                              ((unsigned int)(v.y & 1) << 8) |
                              ((unsigned int)(v.z & 1) << 16) |
                              ((unsigned int)(v.w & 1) << 24);
                }
        }
        // transpose each 4x4 byte block via v_perm (verified recipe), ±1,
        // write n-major into LDS: word [n][kq4] = bytes k=k0+kq4*4..+3.
        #pragma unroll
        for (int w = 0; w < 4; ++w) {
            unsigned int a0 = b[0][w], a1 = b[1][w], a2 = b[2][w], a3 = b[3][w];
            unsigned int x0 = __builtin_amdgcn_perm(a1, a0, 0x05010400u);
            unsigned int x1 = __builtin_amdgcn_perm(a3, a2, 0x05010400u);
            unsigned int x2 = __builtin_amdgcn_perm(a1, a0, 0x07030602u);
            unsigned int x3 = __builtin_amdgcn_perm(a3, a2, 0x07030602u);
            unsigned int c0 = __builtin_amdgcn_perm(x1, x0, 0x05040100u);
            unsigned int c1 = __builtin_amdgcn_perm(x1, x0, 0x07060302u);
            unsigned int c2 = __builtin_amdgcn_perm(x3, x2, 0x05040100u);
            unsigned int c3 = __builtin_amdgcn_perm(x3, x2, 0x07060302u);
            tl[nq16 + w * 4 + 0][kq4] = to_pm1(c0);
            tl[nq16 + w * 4 + 1][kq4] = to_pm1(c1);
            tl[nq16 + w * 4 + 2][kq4] = to_pm1(c2);
            tl[nq16 + w * 4 + 3][kq4] = to_pm1(c3);
        }
        __syncthreads();

        // stage 2: frag-major out. Wave wvp writes chunks idx = wvp*4+j:
        // nb-local = idx>>3, kp-local = idx&7. Lane l holds
        // (n = nb*32 + (l&31), k-half l>>5) -> 16B; 1KB coalesced per chunk.
        const int l   = t2 & 63;
        const int wvp = t2 >> 6;
        #pragma unroll
        for (int j = 0; j < 4; ++j) {
            const int idxc = wvp * 4 + j;          // 0..15
            const int nbl  = idxc >> 3;            // 0..1
            const int kpl  = idxc & 7;             // 0..7
            uint4 v = *(const uint4*)&tl[nbl * 32 + (l & 31)]
                                       [kpl * 8 + (l >> 5) * 4];
            const size_t off = (size_t)((n0 >> 5) + nbl) * 131072 +
                               (size_t)((k0 >> 5) + kpl) * 1024 + l * 16;
            *(uint4*)(m8Tf + off) = v;
        }
    }
}

// i8 MFMA GEMM (R21/R22 verbatim): 256(m)x128(n) block tile, 8 waves =
// 2m x 2n x 2k(split-K), wave tile 128x64 (acc[4][2]). BK=128 chunks (32),
// triple-buffer LDS (144 KB), depth-2 prefetch, one raw s_barrier per chunk
// with counted vmcnt(6). Split-K combine via LDS pool. bm = flat&7 = XCD.
__global__ __launch_bounds__(512)
void bgemm(const char* __restrict__ x8f,
           const char* __restrict__ m8Tf,
           const int* __restrict__ thr,
           int* __restrict__ out) {
    const int flat = blockIdx.x;                   // 0..255
    const int bm   = flat & 7;                     // XCD id = A panel
    const int bn   = flat >> 3;                    // 0..31
    const int b0   = bm * 256;                     // m
    const int o0   = bn * 128;                     // n

    const int tid  = threadIdx.x;
    const int lane = tid & 63;
    const int wv   = tid >> 6;           // 0..7
    const int im   = wv & 1;
    const int in_  = (wv >> 1) & 1;
    const int kh   = wv >> 2;            // split-K half
    const int wm   = im * 128;           // wave tile m origin
    const int wn   = in_ * 64;           // wave tile n origin
    const int l31  = lane & 31;
    const int lh   = lane >> 5;

    // 3 buffers x (A 32KB + B 16KB) = 144 KB; pool reused for split-K combine.
    __shared__ __align__(16) char lds[3 * 49152];

    // stage chunk-step c -> buf: 48 x 1KB frag chunks, all linear.
    // 6 global_load_lds per thread (A:4, B:2).
    auto stage = [&](int c, int buf) {
        char* bufA = lds + buf * 49152;
        char* bufB = bufA + 32768;
        const int kp0 = c * 4;
        #pragma unroll
        for (int j = 0; j < 4; ++j) {              // A: 4 chunks/wave
            const int ci = wv * 4 + j;             // 0..31
            const int rb = ci >> 2, kp = ci & 3;
            async_load16(x8f + (size_t)(bm * 8 + rb) * 131072 +
                               (size_t)(kp0 + kp) * 1024 + lane * 16,
                         bufA + ci * 1024 + lane * 16);
        }
        #pragma unroll
        for (int j = 0; j < 2; ++j) {              // B: 2 chunks/wave
            const int ci = wv * 2 + j;             // 0..15
            const int nb = ci >> 2, kp = ci & 3;
            async_load16(m8Tf + (size_t)(bn * 4 + nb) * 131072 +
                                (size_t)(kp0 + kp) * 1024 + lane * 16,
                         bufB + ci * 1024 + lane * 16);
        }
    };

    v16i acc[4][2];
    #pragma unroll
    for (int t = 0; t < 4; ++t)
        #pragma unroll
        for (int u = 0; u < 2; ++u)
            acc[t][u] = (v16i)(0);

    // prologue: depth-2 prefetch (12 loads/thread in flight).
    stage(0, 0);
    stage(1, 1);

    for (int c = 0; c < 32; ++c) {
        // drain exactly stage(c): leave stage(c+1) (6 loads) in flight.
        if (c < 31) asm volatile("s_waitcnt vmcnt(6)" ::: "memory");
        else        asm volatile("s_waitcnt vmcnt(0)" ::: "memory");
        __builtin_amdgcn_s_barrier();  // stage(c) visible everywhere; all
                                       // waves done computing c-1 -> buf free
        if (c < 30) stage(c + 2, (c + 2) % 3);

        const char* bufA = lds + (c % 3) * 49152;
        const char* bufB = bufA + 32768;
        #pragma unroll
        for (int ks = 0; ks < 2; ++ks) {
            const int kp = kh * 2 + ks;            // this wave's kp chunk
            v4i aF[4], bF[2];
            #pragma unroll
            for (int t = 0; t < 4; ++t)
                aF[t] = *(const v4i*)&bufA[((im * 4 + t) * 4 + kp) * 1024
                                           + lane * 16];
            #pragma unroll
            for (int u = 0; u < 2; ++u)
                bF[u] = *(const v4i*)&bufB[((in_ * 2 + u) * 4 + kp) * 1024
                                           + lane * 16];
            #pragma unroll
            for (int t = 0; t < 4; ++t)
                #pragma unroll
                for (int u = 0; u < 2; ++u)
                    acc[t][u] = __builtin_amdgcn_mfma_i32_32x32x32_i8(
                        aF[t], bF[u], acc[t][u], 0, 0, 0);
        }
    }
    __syncthreads();   // all compute done; lds pool free for combine

    // ---- split-K combine. Pair p = (im,in_): waves (p, kh=0) and (p, kh=1)
    // computed the same 128x64 tile over disjoint K halves. Each wave gives
    // one 64-row half via LDS and keeps the other: h=0 keeps t0,1 gives t2,3;
    // h=1 keeps t2,3 gives t0,1. Pool: per pair 8192 i32 (2 halves x 4096).
    int* pool = (int*)lds;                         // 128 KB used
    const int p = wv & 3;
    {
        const int give0 = kh ? 0 : 2;              // first given t
        const int bw_ = p * 8192 + (kh ? 0 : 1) * 4096;
        #pragma unroll
        for (int tt = 0; tt < 2; ++tt) {
            const int t = give0 + tt;
            #pragma unroll
            for (int u = 0; u < 2; ++u)
                #pragma unroll
                for (int r = 0; r < 16; ++r) {
                    const int rowl = (r & 3) + 8 * (r >> 2) + 4 * lh;
                    pool[bw_ + (tt * 32 + rowl) * 64 + u * 32 + l31] = acc[t][u][r];
                }
        }
    }
    __syncthreads();
    const int keep0 = kh ? 2 : 0;
    const int br_ = p * 8192 + kh * 4096;          // partner's gift = my kept rows
    #pragma unroll
    for (int tt = 0; tt < 2; ++tt) {
        const int t = keep0 + tt;
        #pragma unroll
        for (int u = 0; u < 2; ++u)
            #pragma unroll
            for (int r = 0; r < 16; ++r) {
                const int rowl = (r & 3) + 8 * (r >> 2) + 4 * lh;
                acc[t][u][r] += pool[br_ + (tt * 32 + rowl) * 64 + u * 32 + l31];
            }
    }

    // epilogue: out = (dot± > 2*thr - 4096).
    // C/D layout (verified R7): col = lane&31; row = (reg&3)+8*(reg>>2)+4*(lane>>5).
    #pragma unroll
    for (int u = 0; u < 2; ++u) {
        const int o   = o0 + wn + u * 32 + l31;
        const int lim = 2 * thr[o] - DIN;
        #pragma unroll
        for (int tt = 0; tt < 2; ++tt) {
            const int t = keep0 + tt;
            #pragma unroll
            for (int r = 0; r < 16; ++r) {
                const int rowl = (r & 3) + 8 * (r >> 2) + 4 * lh;
                const int b    = b0 + wm + kh * 64 + tt * 32 + rowl;
                out[(size_t)b * DOUT + o] = (acc[t][u][r] > lim) ? 1 : 0;
            }
        }
    }
}

extern "C" void kernel_launch(void* const* d_in, const int* in_sizes, int n_in,
                              void* d_out, int out_size, void* d_ws, size_t ws_size,
                              hipStream_t stream) {
    const int* x          = (const int*)d_in[0];
    const void* masks     = d_in[1];           // bool: u8 or int32 (detected inline)
    const int* thresholds = (const int*)d_in[2];
    int* out              = (int*)d_out;

    char* x8f  = (char*)d_ws;                         // 8 MB frag-major
    char* m8Tf = (char*)d_ws + ((size_t)8 << 20);     // 16 MB frag-major

    pack_all<<<768, 512, 0, stream>>>(x, masks, x8f, m8Tf);
    bgemm<<<256, 512, 0, stream>>>(x8f, m8Tf, thresholds, out);
}